// Round 1
// baseline (663.321 us; speedup 1.0000x reference)
//
#include <hip/hip_runtime.h>
#include <math.h>

#define NB 256      // batch / time steps
#define NV 100      // visits
#define NC 40       // codes per visit
#define NE 128      // embed dim (LSTM "batch")
#define NH 100      // hidden (== feat)
#define NG 400      // 4*NH

// ws layout (float elements)
#define OFF_SUM   0
#define N_SUM     (NB*NV*NE)                 // 3,276,800  (x2 viewed [32768][100])
#define OFF_PRE   (OFF_SUM + N_SUM)
#define N_PRE     (NB*NE*NG)                 // 13,107,200
#define OFF_TRUH  (OFF_PRE + N_PRE)
#define N_TRUH    (NB*NE)                    // 32,768
#define OFF_LAST  (OFF_TRUH + N_TRUH)        // ints, 256

// ---------------------------------------------------------------- kernel 1
// masked embedding sum  +  last-visit segment max
__global__ __launch_bounds__(128) void k_embed(
    const int* __restrict__ diag, const float* __restrict__ mask,
    const float* __restrict__ table, float* __restrict__ sumembed,
    int* __restrict__ last) {
  int bv = blockIdx.x;              // 0..25599
  int b  = bv / NV;
  int v  = bv - b * NV;
  int base = bv * NC;
  int e = threadIdx.x;              // 0..127
  float acc = 0.f;
  float msum = 0.f;
  for (int c = 0; c < NC; ++c) {
    float m = mask[base + c];       // wave-uniform -> scalar load
    msum += m;
    if (m != 0.f) {                 // uniform branch, skips dead gathers
      int idx = diag[base + c];     // wave-uniform
      acc = fmaf(m, table[idx * NE + e], acc);
    }
  }
  sumembed[bv * NE + e] = acc;
  if (e == 0 && msum > 0.f) atomicMax(&last[b], v);
}

// ---------------------------------------------------------------- kernel 2
// pre[t*128+e][j] = x2[m][:] . W_ih[j][:] + (b_ih[j]+b_hh[j])
// M=32768, K=100, N=400.  64x64 tiles, 4x4 register tiles.
__global__ __launch_bounds__(256) void k_pregemm(
    const float* __restrict__ x2, const float* __restrict__ Wih,
    const float* __restrict__ bih, const float* __restrict__ bhh,
    float* __restrict__ pre) {
  __shared__ __align__(16) float As[100][68];   // [k][m], stride 68 => 16B aligned rows
  __shared__ __align__(16) float Bs[100][68];   // [k][n]
  __shared__ __align__(16) float bias_s[64];
  const int m0 = blockIdx.x * 64;
  const int n0 = blockIdx.y * 64;
  const int tid = threadIdx.x;

  for (int idx = tid; idx < 6400; idx += 256) {
    int m = idx / 100, k = idx - m * 100;
    As[k][m] = x2[(m0 + m) * 100 + k];          // coalesced along k
  }
  for (int idx = tid; idx < 6400; idx += 256) {
    int n = idx / 100, k = idx - n * 100;
    int j = n0 + n;
    Bs[k][n] = (j < NG) ? Wih[j * 100 + k] : 0.f;
  }
  if (tid < 64) {
    int j = n0 + tid;
    bias_s[tid] = (j < NG) ? (bih[j] + bhh[j]) : 0.f;
  }
  __syncthreads();

  const int tm = tid & 15, tn = tid >> 4;       // 16x16 thread grid, 4x4 each
  float acc[4][4] = {};
  #pragma unroll 4
  for (int k = 0; k < 100; ++k) {
    float4 a  = *(const float4*)&As[k][tm * 4];
    float4 bb = *(const float4*)&Bs[k][tn * 4];
    acc[0][0] = fmaf(a.x, bb.x, acc[0][0]); acc[0][1] = fmaf(a.x, bb.y, acc[0][1]);
    acc[0][2] = fmaf(a.x, bb.z, acc[0][2]); acc[0][3] = fmaf(a.x, bb.w, acc[0][3]);
    acc[1][0] = fmaf(a.y, bb.x, acc[1][0]); acc[1][1] = fmaf(a.y, bb.y, acc[1][1]);
    acc[1][2] = fmaf(a.y, bb.z, acc[1][2]); acc[1][3] = fmaf(a.y, bb.w, acc[1][3]);
    acc[2][0] = fmaf(a.z, bb.x, acc[2][0]); acc[2][1] = fmaf(a.z, bb.y, acc[2][1]);
    acc[2][2] = fmaf(a.z, bb.z, acc[2][2]); acc[2][3] = fmaf(a.z, bb.w, acc[2][3]);
    acc[3][0] = fmaf(a.w, bb.x, acc[3][0]); acc[3][1] = fmaf(a.w, bb.y, acc[3][1]);
    acc[3][2] = fmaf(a.w, bb.z, acc[3][2]); acc[3][3] = fmaf(a.w, bb.w, acc[3][3]);
  }

  if (n0 + tn * 4 < NG) {                       // whole float4 valid or none (400%4==0)
    float4 bb = *(const float4*)&bias_s[tn * 4];
    #pragma unroll
    for (int im = 0; im < 4; ++im) {
      int m = m0 + tm * 4 + im;
      float4 st;
      st.x = acc[im][0] + bb.x; st.y = acc[im][1] + bb.y;
      st.z = acc[im][2] + bb.z; st.w = acc[im][3] + bb.w;
      *(float4*)&pre[m * NG + n0 + tn * 4] = st;
    }
  }
}

// ---------------------------------------------------------------- kernel 3
// sequential LSTM: 128 blocks (one per e-row), 512 threads.
// thread j<400 owns W_hh row j in registers; threads 0..99 own cell c[k].
__device__ __forceinline__ float fast_sigmoid(float x) {
  return 1.f / (1.f + __expf(-x));
}
__device__ __forceinline__ float fast_tanh(float x) {
  float ax = fabsf(x);
  float e  = __expf(-2.f * ax);
  float t  = (1.f - e) / (1.f + e);
  return x < 0.f ? -t : t;
}

__global__ __launch_bounds__(512) void k_lstm(
    const float* __restrict__ pre, const float* __restrict__ Whh,
    const int* __restrict__ last, float* __restrict__ truh) {
  __shared__ __align__(16) float h_s[100];
  __shared__ float g_s[NG];
  const int e = blockIdx.x;         // 0..127
  const int j = threadIdx.x;        // active < 400

  float w[100];
  if (j < NG) {
    #pragma unroll
    for (int k = 0; k < 100; ++k) w[k] = Whh[j * 100 + k];
  }
  if (j < NH) h_s[j] = 0.f;
  float c = 0.f;                    // cell state for thread j<100

  const float* pbase = pre + e * NG + j;        // + t*51200 per step
  float p0 = (j < NG) ? pbase[0]     : 0.f;
  float p1 = (j < NG) ? pbase[51200] : 0.f;
  __syncthreads();

  for (int t = 0; t < NB; ++t) {
    float p2 = (j < NG && t + 2 < NB) ? pbase[(t + 2) * 51200] : 0.f;

    if (j < NG) {
      float acc = p0;
      const float4* h4 = (const float4*)h_s;
      #pragma unroll
      for (int k4 = 0; k4 < 25; ++k4) {
        float4 hv = h4[k4];                     // uniform broadcast b128
        acc = fmaf(hv.x, w[4 * k4 + 0], acc);
        acc = fmaf(hv.y, w[4 * k4 + 1], acc);
        acc = fmaf(hv.z, w[4 * k4 + 2], acc);
        acc = fmaf(hv.w, w[4 * k4 + 3], acc);
      }
      float act = (j >= 200 && j < 300) ? fast_tanh(acc) : fast_sigmoid(acc);
      g_s[j] = act;
    }
    __syncthreads();                            // gates visible

    if (j < NH) {
      float ig = g_s[j], fg = g_s[100 + j], gg = g_s[200 + j], og = g_s[300 + j];
      c = fmaf(fg, c, ig * gg);
      float h = og * fast_tanh(c);
      h_s[j] = h;
      if (j == last[t]) truh[t * NE + e] = h;   // hs[b=t, e, last[t]]
    }
    __syncthreads();                            // h_s(t) visible for step t+1

    p0 = p1; p1 = p2;
  }
}

// ---------------------------------------------------------------- kernel 4
// out[b] = sigmoid( truh[b,:] . fc_w + fc_b )
__global__ __launch_bounds__(128) void k_fc(
    const float* __restrict__ truh, const float* __restrict__ fcw,
    const float* __restrict__ fcb, float* __restrict__ out) {
  int b = blockIdx.x, t = threadIdx.x;
  float v = truh[b * NE + t] * fcw[t];
  #pragma unroll
  for (int o = 32; o > 0; o >>= 1) v += __shfl_down(v, o);
  __shared__ float s[2];
  if ((t & 63) == 0) s[t >> 6] = v;
  __syncthreads();
  if (t == 0) {
    float sum = s[0] + s[1] + fcb[0];
    out[b] = 1.f / (1.f + __expf(-sum));
  }
}

// ---------------------------------------------------------------- launch
extern "C" void kernel_launch(void* const* d_in, const int* in_sizes, int n_in,
                              void* d_out, int out_size, void* d_ws, size_t ws_size,
                              hipStream_t stream) {
  (void)in_sizes; (void)n_in; (void)out_size; (void)ws_size;
  const int*   diag  = (const int*)d_in[0];
  const float* mask  = (const float*)d_in[1];
  const float* table = (const float*)d_in[2];
  const float* Wih   = (const float*)d_in[3];
  const float* Whh   = (const float*)d_in[4];
  const float* bih   = (const float*)d_in[5];
  const float* bhh   = (const float*)d_in[6];
  const float* fcw   = (const float*)d_in[7];
  const float* fcb   = (const float*)d_in[8];

  float* ws       = (float*)d_ws;
  float* sumembed = ws + OFF_SUM;
  float* pre      = ws + OFF_PRE;
  float* truh     = ws + OFF_TRUH;
  int*   last     = (int*)(ws + OFF_LAST);
  float* out      = (float*)d_out;

  hipMemsetAsync(last, 0, NB * sizeof(int), stream);
  k_embed  <<<dim3(NB * NV), dim3(128), 0, stream>>>(diag, mask, table, sumembed, last);
  k_pregemm<<<dim3(512, 7),  dim3(256), 0, stream>>>(sumembed, Wih, bih, bhh, pre);
  k_lstm   <<<dim3(NE),      dim3(512), 0, stream>>>(pre, Whh, last, truh);
  k_fc     <<<dim3(NB),      dim3(128), 0, stream>>>(truh, fcw, fcb, out);
}

// Round 3
// 563.945 us; speedup vs baseline: 1.1762x; 1.1762x over previous
//
#include <hip/hip_runtime.h>
#include <math.h>

#define NB 256      // batch / time steps
#define NV 100      // visits
#define NC 40       // codes per visit
#define NE 128      // embed dim (LSTM "batch")
#define NH 100      // hidden (== feat)
#define NG 400      // 4*NH

// ws layout (float elements)
#define OFF_SUM   0
#define N_SUM     (NB*NV*NE)                 // 3,276,800  (x2 viewed [32768][100])
#define OFF_PRE   (OFF_SUM + N_SUM)
#define N_PRE     (NB*NE*NG)                 // 13,107,200
#define OFF_TRUH  (OFF_PRE + N_PRE)
#define N_TRUH    (NB*NE)                    // 32,768
#define OFF_LAST  (OFF_TRUH + N_TRUH)        // ints, 256

// ---------------------------------------------------------------- kernel 1
// masked embedding sum  +  last-visit segment max
__global__ __launch_bounds__(128) void k_embed(
    const int* __restrict__ diag, const float* __restrict__ mask,
    const float* __restrict__ table, float* __restrict__ sumembed,
    int* __restrict__ last) {
  int bv = blockIdx.x;              // 0..25599
  int b  = bv / NV;
  int v  = bv - b * NV;
  int base = bv * NC;
  int e = threadIdx.x;              // 0..127
  float acc = 0.f;
  float msum = 0.f;
  for (int c = 0; c < NC; ++c) {
    float m = mask[base + c];       // wave-uniform -> scalar load
    msum += m;
    if (m != 0.f) {                 // uniform branch, skips dead gathers
      int idx = diag[base + c];     // wave-uniform
      acc = fmaf(m, table[idx * NE + e], acc);
    }
  }
  sumembed[bv * NE + e] = acc;
  if (e == 0 && msum > 0.f) atomicMax(&last[b], v);
}

// ---------------------------------------------------------------- kernel 2
// pre[t*128+e][j] = x2[m][:] . W_ih[j][:] + (b_ih[j]+b_hh[j])
// M=32768, K=100, N=400.  64x64 tiles, 4x4 register tiles.
__global__ __launch_bounds__(256) void k_pregemm(
    const float* __restrict__ x2, const float* __restrict__ Wih,
    const float* __restrict__ bih, const float* __restrict__ bhh,
    float* __restrict__ pre) {
  __shared__ __align__(16) float As[100][68];   // [k][m], stride 68 => 16B aligned rows
  __shared__ __align__(16) float Bs[100][68];   // [k][n]
  __shared__ __align__(16) float bias_s[64];
  const int m0 = blockIdx.x * 64;
  const int n0 = blockIdx.y * 64;
  const int tid = threadIdx.x;

  for (int idx = tid; idx < 6400; idx += 256) {
    int m = idx / 100, k = idx - m * 100;
    As[k][m] = x2[(m0 + m) * 100 + k];          // coalesced along k
  }
  for (int idx = tid; idx < 6400; idx += 256) {
    int n = idx / 100, k = idx - n * 100;
    int j = n0 + n;
    Bs[k][n] = (j < NG) ? Wih[j * 100 + k] : 0.f;
  }
  if (tid < 64) {
    int j = n0 + tid;
    bias_s[tid] = (j < NG) ? (bih[j] + bhh[j]) : 0.f;
  }
  __syncthreads();

  const int tm = tid & 15, tn = tid >> 4;       // 16x16 thread grid, 4x4 each
  float acc[4][4] = {};
  #pragma unroll 4
  for (int k = 0; k < 100; ++k) {
    float4 a  = *(const float4*)&As[k][tm * 4];
    float4 bb = *(const float4*)&Bs[k][tn * 4];
    acc[0][0] = fmaf(a.x, bb.x, acc[0][0]); acc[0][1] = fmaf(a.x, bb.y, acc[0][1]);
    acc[0][2] = fmaf(a.x, bb.z, acc[0][2]); acc[0][3] = fmaf(a.x, bb.w, acc[0][3]);
    acc[1][0] = fmaf(a.y, bb.x, acc[1][0]); acc[1][1] = fmaf(a.y, bb.y, acc[1][1]);
    acc[1][2] = fmaf(a.y, bb.z, acc[1][2]); acc[1][3] = fmaf(a.y, bb.w, acc[1][3]);
    acc[2][0] = fmaf(a.z, bb.x, acc[2][0]); acc[2][1] = fmaf(a.z, bb.y, acc[2][1]);
    acc[2][2] = fmaf(a.z, bb.z, acc[2][2]); acc[2][3] = fmaf(a.z, bb.w, acc[2][3]);
    acc[3][0] = fmaf(a.w, bb.x, acc[3][0]); acc[3][1] = fmaf(a.w, bb.y, acc[3][1]);
    acc[3][2] = fmaf(a.w, bb.z, acc[3][2]); acc[3][3] = fmaf(a.w, bb.w, acc[3][3]);
  }

  if (n0 + tn * 4 < NG) {                       // whole float4 valid or none (400%4==0)
    float4 bb = *(const float4*)&bias_s[tn * 4];
    #pragma unroll
    for (int im = 0; im < 4; ++im) {
      int m = m0 + tm * 4 + im;
      float4 st;
      st.x = acc[im][0] + bb.x; st.y = acc[im][1] + bb.y;
      st.z = acc[im][2] + bb.z; st.w = acc[im][3] + bb.w;
      *(float4*)&pre[m * NG + n0 + tn * 4] = st;
    }
  }
}

// ---------------------------------------------------------------- kernel 3
// sequential LSTM: 128 blocks (one per e-row), 512 threads.
// thread j<400 owns W_hh row j in registers; threads 0..99 own cell c[k].
// __launch_bounds__(512, 2): 2 waves/EU -> 256-VGPR cap. The default cap
// (64 VGPR, R1 counters) spilled w[100] to scratch -> 382us L2-bound kernel.
__device__ __forceinline__ float fast_sigmoid(float x) {
  return 1.f / (1.f + __expf(-x));
}
__device__ __forceinline__ float fast_tanh(float x) {
  float ax = fabsf(x);
  float e  = __expf(-2.f * ax);
  float t  = (1.f - e) / (1.f + e);
  return x < 0.f ? -t : t;
}

__global__ __launch_bounds__(512, 2) void k_lstm(
    const float* __restrict__ pre, const float* __restrict__ Whh,
    const int* __restrict__ last, float* __restrict__ truh) {
  __shared__ __align__(16) float h_s[100];
  __shared__ float g_s[NG];
  __shared__ int   last_s[NB];
  const int e = blockIdx.x;         // 0..127
  const int j = threadIdx.x;        // active < 400

  float w[100];
  if (j < NG) {
    #pragma unroll
    for (int k = 0; k < 100; ++k) w[k] = Whh[j * 100 + k];
  }
  if (j < NH) h_s[j] = 0.f;
  if (j < NB) last_s[j] = last[j];  // stage once; avoids per-step global read
  float c = 0.f;                    // cell state for thread j<100

  const float* pbase = pre + e * NG + j;        // + t*51200 per step
  float p0 = (j < NG) ? pbase[0]         : 0.f;
  float p1 = (j < NG) ? pbase[51200]     : 0.f;
  float p2 = (j < NG) ? pbase[2 * 51200] : 0.f;
  __syncthreads();

  for (int t = 0; t < NB; ++t) {
    float p3 = (j < NG && t + 3 < NB) ? pbase[(t + 3) * 51200] : 0.f;

    if (j < NG) {
      // 4 independent accumulator chains: break the 100-deep FMA dep chain.
      // Main loop covers k=0..95 (k4=0,4,8,12,16,20 -> 6 full 16-elem blocks);
      // tail covers k=96..99 exactly once. (R2 bug: bound 25 ran a full block
      // at k4=24, reading h4[25..27] and w[100..111] OOB -> NaN.)
      float a0 = p0, a1 = 0.f, a2 = 0.f, a3 = 0.f;
      const float4* h4 = (const float4*)h_s;
      #pragma unroll
      for (int k4 = 0; k4 < 24; k4 += 4) {
        float4 h0 = h4[k4], h1v = h4[k4 + 1], h2v = h4[k4 + 2], h3v = h4[k4 + 3];
        a0 = fmaf(h0.x,  w[4*k4+0],  a0); a0 = fmaf(h0.y,  w[4*k4+1],  a0);
        a0 = fmaf(h0.z,  w[4*k4+2],  a0); a0 = fmaf(h0.w,  w[4*k4+3],  a0);
        a1 = fmaf(h1v.x, w[4*k4+4],  a1); a1 = fmaf(h1v.y, w[4*k4+5],  a1);
        a1 = fmaf(h1v.z, w[4*k4+6],  a1); a1 = fmaf(h1v.w, w[4*k4+7],  a1);
        a2 = fmaf(h2v.x, w[4*k4+8],  a2); a2 = fmaf(h2v.y, w[4*k4+9],  a2);
        a2 = fmaf(h2v.z, w[4*k4+10], a2); a2 = fmaf(h2v.w, w[4*k4+11], a2);
        a3 = fmaf(h3v.x, w[4*k4+12], a3); a3 = fmaf(h3v.y, w[4*k4+13], a3);
        a3 = fmaf(h3v.z, w[4*k4+14], a3); a3 = fmaf(h3v.w, w[4*k4+15], a3);
      }
      // tail: k = 96..99
      {
        float4 hv = h4[24];
        a0 = fmaf(hv.x, w[96], a0); a1 = fmaf(hv.y, w[97], a1);
        a2 = fmaf(hv.z, w[98], a2); a3 = fmaf(hv.w, w[99], a3);
      }
      float acc = (a0 + a1) + (a2 + a3);
      float act = (j >= 200 && j < 300) ? fast_tanh(acc) : fast_sigmoid(acc);
      g_s[j] = act;
    }
    __syncthreads();                            // gates visible

    if (j < NH) {
      float ig = g_s[j], fg = g_s[100 + j], gg = g_s[200 + j], og = g_s[300 + j];
      c = fmaf(fg, c, ig * gg);
      float h = og * fast_tanh(c);
      h_s[j] = h;
      if (j == last_s[t]) truh[t * NE + e] = h; // hs[b=t, e, last[t]]
    }
    __syncthreads();                            // h_s(t) visible for step t+1

    p0 = p1; p1 = p2; p2 = p3;
  }
}

// ---------------------------------------------------------------- kernel 4
// out[b] = sigmoid( truh[b,:] . fc_w + fc_b )
__global__ __launch_bounds__(128) void k_fc(
    const float* __restrict__ truh, const float* __restrict__ fcw,
    const float* __restrict__ fcb, float* __restrict__ out) {
  int b = blockIdx.x, t = threadIdx.x;
  float v = truh[b * NE + t] * fcw[t];
  #pragma unroll
  for (int o = 32; o > 0; o >>= 1) v += __shfl_down(v, o);
  __shared__ float s[2];
  if ((t & 63) == 0) s[t >> 6] = v;
  __syncthreads();
  if (t == 0) {
    float sum = s[0] + s[1] + fcb[0];
    out[b] = 1.f / (1.f + __expf(-sum));
  }
}

// ---------------------------------------------------------------- launch
extern "C" void kernel_launch(void* const* d_in, const int* in_sizes, int n_in,
                              void* d_out, int out_size, void* d_ws, size_t ws_size,
                              hipStream_t stream) {
  (void)in_sizes; (void)n_in; (void)out_size; (void)ws_size;
  const int*   diag  = (const int*)d_in[0];
  const float* mask  = (const float*)d_in[1];
  const float* table = (const float*)d_in[2];
  const float* Wih   = (const float*)d_in[3];
  const float* Whh   = (const float*)d_in[4];
  const float* bih   = (const float*)d_in[5];
  const float* bhh   = (const float*)d_in[6];
  const float* fcw   = (const float*)d_in[7];
  const float* fcb   = (const float*)d_in[8];

  float* ws       = (float*)d_ws;
  float* sumembed = ws + OFF_SUM;
  float* pre      = ws + OFF_PRE;
  float* truh     = ws + OFF_TRUH;
  int*   last     = (int*)(ws + OFF_LAST);
  float* out      = (float*)d_out;

  hipMemsetAsync(last, 0, NB * sizeof(int), stream);
  k_embed  <<<dim3(NB * NV), dim3(128), 0, stream>>>(diag, mask, table, sumembed, last);
  k_pregemm<<<dim3(512, 7),  dim3(256), 0, stream>>>(sumembed, Wih, bih, bhh, pre);
  k_lstm   <<<dim3(NE),      dim3(512), 0, stream>>>(pre, Whh, last, truh);
  k_fc     <<<dim3(NB),      dim3(128), 0, stream>>>(truh, fcw, fcb, out);
}

// Round 4
// 491.906 us; speedup vs baseline: 1.3485x; 1.1464x over previous
//
#include <hip/hip_runtime.h>
#include <math.h>

#define NB 256      // batch / time steps
#define NV 100      // visits
#define NC 40       // codes per visit
#define NE 128      // embed dim (LSTM "batch")
#define NH 100      // hidden (== feat)
#define NG 400      // 4*NH

// ws layout (float elements)
#define OFF_SUM   0
#define N_SUM     (NB*NV*NE)                 // 3,276,800  (x2 viewed [32768][100])
#define OFF_PRE   (OFF_SUM + N_SUM)
#define N_PRE     (NB*NE*NG)                 // 13,107,200
#define OFF_TRUH  (OFF_PRE + N_PRE)
#define N_TRUH    (NB*NE)                    // 32,768
#define OFF_LAST  (OFF_TRUH + N_TRUH)        // ints, 256

// ---------------------------------------------------------------- kernel 1
// masked embedding sum  +  last-visit segment max
__global__ __launch_bounds__(128) void k_embed(
    const int* __restrict__ diag, const float* __restrict__ mask,
    const float* __restrict__ table, float* __restrict__ sumembed,
    int* __restrict__ last) {
  int bv = blockIdx.x;              // 0..25599
  int b  = bv / NV;
  int v  = bv - b * NV;
  int base = bv * NC;
  int e = threadIdx.x;              // 0..127
  float acc = 0.f;
  float msum = 0.f;
  for (int c = 0; c < NC; ++c) {
    float m = mask[base + c];       // wave-uniform -> scalar load
    msum += m;
    if (m != 0.f) {                 // uniform branch, skips dead gathers
      int idx = diag[base + c];     // wave-uniform
      acc = fmaf(m, table[idx * NE + e], acc);
    }
  }
  sumembed[bv * NE + e] = acc;
  if (e == 0 && msum > 0.f) atomicMax(&last[b], v);
}

// ---------------------------------------------------------------- kernel 2
// pre[t*128+e][j] = x2[m][:] . W_ih[j][:] + (b_ih[j]+b_hh[j])
// M=32768, K=100, N=400.  64x64 tiles, 4x4 register tiles.
__global__ __launch_bounds__(256) void k_pregemm(
    const float* __restrict__ x2, const float* __restrict__ Wih,
    const float* __restrict__ bih, const float* __restrict__ bhh,
    float* __restrict__ pre) {
  __shared__ __align__(16) float As[100][68];   // [k][m], stride 68 => 16B aligned rows
  __shared__ __align__(16) float Bs[100][68];   // [k][n]
  __shared__ __align__(16) float bias_s[64];
  const int m0 = blockIdx.x * 64;
  const int n0 = blockIdx.y * 64;
  const int tid = threadIdx.x;

  for (int idx = tid; idx < 6400; idx += 256) {
    int m = idx / 100, k = idx - m * 100;
    As[k][m] = x2[(m0 + m) * 100 + k];          // coalesced along k
  }
  for (int idx = tid; idx < 6400; idx += 256) {
    int n = idx / 100, k = idx - n * 100;
    int j = n0 + n;
    Bs[k][n] = (j < NG) ? Wih[j * 100 + k] : 0.f;
  }
  if (tid < 64) {
    int j = n0 + tid;
    bias_s[tid] = (j < NG) ? (bih[j] + bhh[j]) : 0.f;
  }
  __syncthreads();

  const int tm = tid & 15, tn = tid >> 4;       // 16x16 thread grid, 4x4 each
  float acc[4][4] = {};
  #pragma unroll 4
  for (int k = 0; k < 100; ++k) {
    float4 a  = *(const float4*)&As[k][tm * 4];
    float4 bb = *(const float4*)&Bs[k][tn * 4];
    acc[0][0] = fmaf(a.x, bb.x, acc[0][0]); acc[0][1] = fmaf(a.x, bb.y, acc[0][1]);
    acc[0][2] = fmaf(a.x, bb.z, acc[0][2]); acc[0][3] = fmaf(a.x, bb.w, acc[0][3]);
    acc[1][0] = fmaf(a.y, bb.x, acc[1][0]); acc[1][1] = fmaf(a.y, bb.y, acc[1][1]);
    acc[1][2] = fmaf(a.y, bb.z, acc[1][2]); acc[1][3] = fmaf(a.y, bb.w, acc[1][3]);
    acc[2][0] = fmaf(a.z, bb.x, acc[2][0]); acc[2][1] = fmaf(a.z, bb.y, acc[2][1]);
    acc[2][2] = fmaf(a.z, bb.z, acc[2][2]); acc[2][3] = fmaf(a.z, bb.w, acc[2][3]);
    acc[3][0] = fmaf(a.w, bb.x, acc[3][0]); acc[3][1] = fmaf(a.w, bb.y, acc[3][1]);
    acc[3][2] = fmaf(a.w, bb.z, acc[3][2]); acc[3][3] = fmaf(a.w, bb.w, acc[3][3]);
  }

  if (n0 + tn * 4 < NG) {                       // whole float4 valid or none (400%4==0)
    float4 bb = *(const float4*)&bias_s[tn * 4];
    #pragma unroll
    for (int im = 0; im < 4; ++im) {
      int m = m0 + tm * 4 + im;
      float4 st;
      st.x = acc[im][0] + bb.x; st.y = acc[im][1] + bb.y;
      st.z = acc[im][2] + bb.z; st.w = acc[im][3] + bb.w;
      *(float4*)&pre[m * NG + n0 + tn * 4] = st;
    }
  }
}

// ---------------------------------------------------------------- kernel 3
// sequential LSTM: 128 blocks (one per e-row), 512 threads.
// thread j<400 owns W_hh row j in 25 NAMED float4 registers (no alloca:
// R1/R3 showed the compiler never promotes `float w[100]` -> scratch ->
// L1-BW-bound at ~2740 cyc/step). Named SSA values must get VGPRs.
// __launch_bounds__(512, 2): 2 waves/EU -> 256-VGPR cap (need ~140).
__device__ __forceinline__ float fast_sigmoid(float x) {
  return 1.f / (1.f + __expf(-x));
}
__device__ __forceinline__ float fast_tanh(float x) {
  float ax = fabsf(x);
  float e  = __expf(-2.f * ax);
  float t  = (1.f - e) / (1.f + e);
  return x < 0.f ? -t : t;
}

#define FMA4(A, W, H)                                                     \
  A = fmaf((H).x, (W).x, A); A = fmaf((H).y, (W).y, A);                   \
  A = fmaf((H).z, (W).z, A); A = fmaf((H).w, (W).w, A)

__global__ __launch_bounds__(512, 2) void k_lstm(
    const float* __restrict__ pre, const float* __restrict__ Whh,
    const int* __restrict__ last, float* __restrict__ truh) {
  __shared__ __align__(16) float h_s[100];
  __shared__ float g_s[NG];
  __shared__ int   last_s[NB];
  const int e = blockIdx.x;         // 0..127
  const int j = threadIdx.x;        // active < 400

  // 25 named float4 = 100 weight VGPRs. Whh row stride 400 B -> 16B aligned.
  float4 w00, w01, w02, w03, w04, w05, w06, w07, w08, w09, w10, w11, w12,
         w13, w14, w15, w16, w17, w18, w19, w20, w21, w22, w23, w24;
  if (j < NG) {
    const float4* wr = (const float4*)(Whh + j * 100);
    w00 = wr[0];  w01 = wr[1];  w02 = wr[2];  w03 = wr[3];  w04 = wr[4];
    w05 = wr[5];  w06 = wr[6];  w07 = wr[7];  w08 = wr[8];  w09 = wr[9];
    w10 = wr[10]; w11 = wr[11]; w12 = wr[12]; w13 = wr[13]; w14 = wr[14];
    w15 = wr[15]; w16 = wr[16]; w17 = wr[17]; w18 = wr[18]; w19 = wr[19];
    w20 = wr[20]; w21 = wr[21]; w22 = wr[22]; w23 = wr[23]; w24 = wr[24];
  }
  if (j < NH) h_s[j] = 0.f;
  if (j < NB) last_s[j] = last[j];  // stage once; avoids per-step global read
  float c = 0.f;                    // cell state for thread j<100

  const float* pbase = pre + e * NG + j;        // + t*51200 per step
  float p0 = (j < NG) ? pbase[0]         : 0.f;
  float p1 = (j < NG) ? pbase[51200]     : 0.f;
  float p2 = (j < NG) ? pbase[2 * 51200] : 0.f;
  __syncthreads();

  for (int t = 0; t < NB; ++t) {
    float p3 = (j < NG && t + 3 < NB) ? pbase[(t + 3) * 51200] : 0.f;

    if (j < NG) {
      // 4 independent accumulator chains; h broadcast from LDS via b128.
      float a0 = p0, a1 = 0.f, a2 = 0.f, a3 = 0.f;
      const float4* h4 = (const float4*)h_s;
      float4 h;
      h = h4[0];  FMA4(a0, w00, h);
      h = h4[1];  FMA4(a1, w01, h);
      h = h4[2];  FMA4(a2, w02, h);
      h = h4[3];  FMA4(a3, w03, h);
      h = h4[4];  FMA4(a0, w04, h);
      h = h4[5];  FMA4(a1, w05, h);
      h = h4[6];  FMA4(a2, w06, h);
      h = h4[7];  FMA4(a3, w07, h);
      h = h4[8];  FMA4(a0, w08, h);
      h = h4[9];  FMA4(a1, w09, h);
      h = h4[10]; FMA4(a2, w10, h);
      h = h4[11]; FMA4(a3, w11, h);
      h = h4[12]; FMA4(a0, w12, h);
      h = h4[13]; FMA4(a1, w13, h);
      h = h4[14]; FMA4(a2, w14, h);
      h = h4[15]; FMA4(a3, w15, h);
      h = h4[16]; FMA4(a0, w16, h);
      h = h4[17]; FMA4(a1, w17, h);
      h = h4[18]; FMA4(a2, w18, h);
      h = h4[19]; FMA4(a3, w19, h);
      h = h4[20]; FMA4(a0, w20, h);
      h = h4[21]; FMA4(a1, w21, h);
      h = h4[22]; FMA4(a2, w22, h);
      h = h4[23]; FMA4(a3, w23, h);
      h = h4[24]; FMA4(a0, w24, h);
      float acc = (a0 + a1) + (a2 + a3);
      float act = (j >= 200 && j < 300) ? fast_tanh(acc) : fast_sigmoid(acc);
      g_s[j] = act;
    }
    __syncthreads();                            // gates visible

    if (j < NH) {
      float ig = g_s[j], fg = g_s[100 + j], gg = g_s[200 + j], og = g_s[300 + j];
      c = fmaf(fg, c, ig * gg);
      float h = og * fast_tanh(c);
      h_s[j] = h;
      if (j == last_s[t]) truh[t * NE + e] = h; // hs[b=t, e, last[t]]
    }
    __syncthreads();                            // h_s(t) visible for step t+1

    p0 = p1; p1 = p2; p2 = p3;
  }
}

// ---------------------------------------------------------------- kernel 4
// out[b] = sigmoid( truh[b,:] . fc_w + fc_b )
__global__ __launch_bounds__(128) void k_fc(
    const float* __restrict__ truh, const float* __restrict__ fcw,
    const float* __restrict__ fcb, float* __restrict__ out) {
  int b = blockIdx.x, t = threadIdx.x;
  float v = truh[b * NE + t] * fcw[t];
  #pragma unroll
  for (int o = 32; o > 0; o >>= 1) v += __shfl_down(v, o);
  __shared__ float s[2];
  if ((t & 63) == 0) s[t >> 6] = v;
  __syncthreads();
  if (t == 0) {
    float sum = s[0] + s[1] + fcb[0];
    out[b] = 1.f / (1.f + __expf(-sum));
  }
}

// ---------------------------------------------------------------- launch
extern "C" void kernel_launch(void* const* d_in, const int* in_sizes, int n_in,
                              void* d_out, int out_size, void* d_ws, size_t ws_size,
                              hipStream_t stream) {
  (void)in_sizes; (void)n_in; (void)out_size; (void)ws_size;
  const int*   diag  = (const int*)d_in[0];
  const float* mask  = (const float*)d_in[1];
  const float* table = (const float*)d_in[2];
  const float* Wih   = (const float*)d_in[3];
  const float* Whh   = (const float*)d_in[4];
  const float* bih   = (const float*)d_in[5];
  const float* bhh   = (const float*)d_in[6];
  const float* fcw   = (const float*)d_in[7];
  const float* fcb   = (const float*)d_in[8];

  float* ws       = (float*)d_ws;
  float* sumembed = ws + OFF_SUM;
  float* pre      = ws + OFF_PRE;
  float* truh     = ws + OFF_TRUH;
  int*   last     = (int*)(ws + OFF_LAST);
  float* out      = (float*)d_out;

  hipMemsetAsync(last, 0, NB * sizeof(int), stream);
  k_embed  <<<dim3(NB * NV), dim3(128), 0, stream>>>(diag, mask, table, sumembed, last);
  k_pregemm<<<dim3(512, 7),  dim3(256), 0, stream>>>(sumembed, Wih, bih, bhh, pre);
  k_lstm   <<<dim3(NE),      dim3(512), 0, stream>>>(pre, Whh, last, truh);
  k_fc     <<<dim3(NB),      dim3(128), 0, stream>>>(truh, fcw, fcb, out);
}